// Round 14
// baseline (188.326 us; speedup 1.0000x reference)
//
#include <hip/hip_runtime.h>

// TsSub: out[b, p, t] = x[b, I[p], t*10] - x[b, J[p], t*10]
// x: (256, 64, 2000) f32, out: (256, 2016, 200) f32, (I,J)=triu_indices(64,k=1)
//
// R14: R13 (one block per batch, 1x amplification, nt stores) + t-halved
// async pipeline: stage half0 via global_load_lds DMA; issue half1 DMA; emit
// half0 (nt stores) while half1 streams; barrier (vmcnt drain); emit half1.
// LDS: two compact [64][100] f32 half-buffers (linear in load order so the
// wave-uniform-base+lane*4 DMA constraint holds; 6400 = 100 full waves).

#define NF     64
#define T_IN   2000
#define NPAIR  2016
#define NB     256
#define TV4    50      // vec4 per out row
#define HV4    25      // vec4 per half out row
#define NT     1024
#define HALF   (NF * 100)   // 6400 samples per half

typedef float fx4 __attribute__((ext_vector_type(4)));
typedef __attribute__((address_space(3))) float       lds_f32;
typedef __attribute__((address_space(1))) const float  g_f32;

__global__ __launch_bounds__(NT)
void ts_sub_pipe(const float* __restrict__ xf, fx4* __restrict__ out) {
    __shared__ __attribute__((aligned(16))) float bufA[HALF];  // 25.6 KB
    __shared__ __attribute__((aligned(16))) float bufB[HALF];  // 25.6 KB
    __shared__ unsigned char pi[NPAIR];
    __shared__ unsigned char pj[NPAIR];

    const int tid  = threadIdx.x;
    const int lane = tid & 63;
    const int b    = blockIdx.x;
    const float* __restrict__ xb = xf + (size_t)b * (NF * T_IN);

    // --- pair table (2 iters/thread) ---
    for (int p = tid; p < NPAIR; p += NT) {
        float d = 16129.0f - 8.0f * (float)p;          // 127^2 - 8p
        int i = (int)((127.0f - sqrtf(d)) * 0.5f);
        if (i < 0) i = 0;
        while (i > 0 && (i * (127 - i)) / 2 > p) --i;
        while (((i + 1) * (126 - i)) / 2 <= p) ++i;
        pi[p] = (unsigned char)i;
        pj[p] = (unsigned char)(p - (i * (127 - i)) / 2 + i + 1);
    }

    // --- stage half0: sample s = x[row, kk*10], DMA to bufA[idx] ---
    #pragma unroll
    for (int it = 0; it < 7; ++it) {
        int idx = it * NT + tid;
        if (idx < HALF) {                       // wave-uniform (HALF%64==0)
            int row = idx / 100;
            int kk  = idx - row * 100;
            __builtin_amdgcn_global_load_lds(
                (g_f32*)(xb + row * T_IN + kk * 10),
                (lds_f32*)(bufA + (idx - lane)), 4, 0, 0);
        }
    }
    __syncthreads();    // drains vmcnt(0): bufA + tables ready

    // --- issue half1 DMA (stays in flight during emit half0) ---
    #pragma unroll
    for (int it = 0; it < 7; ++it) {
        int idx = it * NT + tid;
        if (idx < HALF) {
            int row = idx / 100;
            int kk  = idx - row * 100;
            __builtin_amdgcn_global_load_lds(
                (g_f32*)(xb + row * T_IN + 1000 + kk * 10),
                (lds_f32*)(bufB + (idx - lane)), 4, 0, 0);
        }
    }

    // --- emit half0: 2016 pair half-rows x 25 vec4, nt stores ---
    const fx4* __restrict__ sA = reinterpret_cast<const fx4*>(bufA); // stride 25
    fx4* __restrict__ ob = out + (size_t)b * (NPAIR * TV4);
    {
        int p  = tid / HV4;
        int tl = tid - p * HV4;
        for (int v = tid; v < NPAIR * HV4; v += NT) {   // 50400
            fx4 a = sA[pi[p] * HV4 + tl];
            fx4 c = sA[pj[p] * HV4 + tl];
            __builtin_nontemporal_store(a - c, &ob[(size_t)p * TV4 + tl]);
            p += 40;                           // 1024 = 40*25 + 24
            tl += 24;
            if (tl >= HV4) { tl -= HV4; ++p; }
        }
    }
    __syncthreads();    // drains vmcnt(0): bufB ready

    // --- emit half1 ---
    const fx4* __restrict__ sB = reinterpret_cast<const fx4*>(bufB);
    {
        int p  = tid / HV4;
        int tl = tid - p * HV4;
        for (int v = tid; v < NPAIR * HV4; v += NT) {
            fx4 a = sB[pi[p] * HV4 + tl];
            fx4 c = sB[pj[p] * HV4 + tl];
            __builtin_nontemporal_store(a - c, &ob[(size_t)p * TV4 + HV4 + tl]);
            p += 40;
            tl += 24;
            if (tl >= HV4) { tl -= HV4; ++p; }
        }
    }
}

extern "C" void kernel_launch(void* const* d_in, const int* in_sizes, int n_in,
                              void* d_out, int out_size, void* d_ws, size_t ws_size,
                              hipStream_t stream) {
    const float* x = (const float*)d_in[0];
    float* out = (float*)d_out;
    ts_sub_pipe<<<dim3(NB), dim3(NT), 0, stream>>>(x, (fx4*)out);
}